// Round 1
// baseline (1341.006 us; speedup 1.0000x reference)
//
#include <hip/hip_runtime.h>
#include <cstddef>

#define N_NODES_C 100000
#define N_EDGES_C 1600000
#define IN_CH_C 128
#define HID_CH_C 256
#define OUT_CH_C 128

// ---------------------------------------------------------------------------
// CSR build: counts -> scan -> fill
// ---------------------------------------------------------------------------

__global__ __launch_bounds__(256) void count_kernel(const int* __restrict__ dst,
                                                    int* __restrict__ counts) {
    int e = blockIdx.x * 256 + threadIdx.x;
    if (e < N_EDGES_C) atomicAdd(&counts[dst[e]], 1);
}

// Single block of 1024 threads: chunked inclusive scan (Hillis-Steele on 1024
// partials) -> exclusive row_start + cursor copy.
__global__ __launch_bounds__(1024) void scan_kernel(const int* __restrict__ counts,
                                                    int* __restrict__ row_start,
                                                    int* __restrict__ cursor) {
    __shared__ int sums[1024];
    const int t = threadIdx.x;
    const int CH = 98;  // 98*1024 = 100352 >= 100000
    const int base = t * CH;
    int s = 0;
    for (int i = 0; i < CH; ++i) {
        int idx = base + i;
        if (idx < N_NODES_C) s += counts[idx];
    }
    sums[t] = s;
    __syncthreads();
    for (int off = 1; off < 1024; off <<= 1) {
        int v = (t >= off) ? sums[t - off] : 0;
        __syncthreads();
        sums[t] += v;
        __syncthreads();
    }
    int run = sums[t] - s;  // exclusive prefix for this chunk
    for (int i = 0; i < CH; ++i) {
        int idx = base + i;
        if (idx < N_NODES_C) {
            row_start[idx] = run;
            cursor[idx] = run;
            run += counts[idx];
        }
    }
    if (t == 1023) row_start[N_NODES_C] = sums[1023];
}

__global__ __launch_bounds__(256) void fill_kernel(const int* __restrict__ src,
                                                   const int* __restrict__ dst,
                                                   int* __restrict__ cursor,
                                                   int* __restrict__ edge_src) {
    int e = blockIdx.x * 256 + threadIdx.x;
    if (e < N_EDGES_C) {
        int d = dst[e];
        int pos = atomicAdd(&cursor[d], 1);
        edge_src[pos] = src[e];
    }
}

// ---------------------------------------------------------------------------
// Mean aggregation: one wave (64 lanes) per destination node, gather over its
// incoming edges. C=128 -> float2/lane, C=256 -> float4/lane. No atomics.
// ---------------------------------------------------------------------------

__global__ __launch_bounds__(256) void agg_mean128(const float* __restrict__ x,
                                                   const int* __restrict__ row_start,
                                                   const int* __restrict__ edge_src,
                                                   float* __restrict__ mean) {
    int node = blockIdx.x * 4 + (threadIdx.x >> 6);
    int lane = threadIdx.x & 63;
    if (node >= N_NODES_C) return;
    int beg = row_start[node];
    int end = row_start[node + 1];
    float ax = 0.f, ay = 0.f;
    for (int j = beg; j < end; ++j) {
        int s = edge_src[j];
        const float2 v = *(const float2*)(x + (size_t)s * 128 + lane * 2);
        ax += v.x;
        ay += v.y;
    }
    int deg = end - beg;
    float inv = deg > 0 ? 1.f / (float)deg : 0.f;
    *(float2*)(mean + (size_t)node * 128 + lane * 2) = make_float2(ax * inv, ay * inv);
}

__global__ __launch_bounds__(256) void agg_mean256(const float* __restrict__ x,
                                                   const int* __restrict__ row_start,
                                                   const int* __restrict__ edge_src,
                                                   float* __restrict__ mean) {
    int node = blockIdx.x * 4 + (threadIdx.x >> 6);
    int lane = threadIdx.x & 63;
    if (node >= N_NODES_C) return;
    int beg = row_start[node];
    int end = row_start[node + 1];
    float a0 = 0.f, a1 = 0.f, a2 = 0.f, a3 = 0.f;
    for (int j = beg; j < end; ++j) {
        int s = edge_src[j];
        const float4 v = *(const float4*)(x + (size_t)s * 256 + lane * 4);
        a0 += v.x;
        a1 += v.y;
        a2 += v.z;
        a3 += v.w;
    }
    int deg = end - beg;
    float inv = deg > 0 ? 1.f / (float)deg : 0.f;
    *(float4*)(mean + (size_t)node * 256 + lane * 4) =
        make_float4(a0 * inv, a1 * inv, a2 * inv, a3 * inv);
}

// ---------------------------------------------------------------------------
// Dual GEMM: OUT[M x NOUT] = act(A1 @ W1 + A2 @ W2 + bias)
// A1,A2: [M x K] row-major; W1,W2: [K x NOUT] row-major.
// 64x64 block tile, 256 threads, 4x4 microtile, BK=16.
// ---------------------------------------------------------------------------

template <int K, int NOUT, bool RELU>
__global__ __launch_bounds__(256) void gemm_dual(const float* __restrict__ A1,
                                                 const float* __restrict__ W1,
                                                 const float* __restrict__ A2,
                                                 const float* __restrict__ W2,
                                                 const float* __restrict__ bias,
                                                 float* __restrict__ out, int M) {
    __shared__ float As[16][68];  // padded: staging writes 2-way (free), b128 reads aligned
    __shared__ float Bs[16][64];

    const int tid = threadIdx.x;
    const int ty = tid >> 4;   // 0..15 -> row group
    const int tx = tid & 15;   // 0..15 -> col group
    const int m0 = blockIdx.x * 64;
    const int n0 = blockIdx.y * 64;

    float acc[4][4];
#pragma unroll
    for (int i = 0; i < 4; ++i)
#pragma unroll
        for (int j = 0; j < 4; ++j) acc[i][j] = 0.f;

#pragma unroll
    for (int mat = 0; mat < 2; ++mat) {
        const float* __restrict__ A = mat ? A2 : A1;
        const float* __restrict__ W = mat ? W2 : W1;
        for (int k0 = 0; k0 < K; k0 += 16) {
            // stage A chunk: As[kk][m] = A[(m0+m)*K + k0+kk]
#pragma unroll
            for (int r = 0; r < 4; ++r) {
                int linear = r * 256 + tid;
                int m = linear >> 4;
                int kk = linear & 15;
                int row = m0 + m;
                As[kk][m] = (row < M) ? A[(size_t)row * K + k0 + kk] : 0.f;
            }
            // stage B chunk: Bs[kk][n] = W[(k0+kk)*NOUT + n0+n]
#pragma unroll
            for (int r = 0; r < 4; ++r) {
                int linear = r * 256 + tid;
                int kk = linear >> 6;
                int n = linear & 63;
                Bs[kk][n] = W[(size_t)(k0 + kk) * NOUT + n0 + n];
            }
            __syncthreads();
#pragma unroll
            for (int kk = 0; kk < 16; ++kk) {
                const float4 av = *(const float4*)&As[kk][ty * 4];
                const float4 bv = *(const float4*)&Bs[kk][tx * 4];
                acc[0][0] += av.x * bv.x; acc[0][1] += av.x * bv.y;
                acc[0][2] += av.x * bv.z; acc[0][3] += av.x * bv.w;
                acc[1][0] += av.y * bv.x; acc[1][1] += av.y * bv.y;
                acc[1][2] += av.y * bv.z; acc[1][3] += av.y * bv.w;
                acc[2][0] += av.z * bv.x; acc[2][1] += av.z * bv.y;
                acc[2][2] += av.z * bv.z; acc[2][3] += av.z * bv.w;
                acc[3][0] += av.w * bv.x; acc[3][1] += av.w * bv.y;
                acc[3][2] += av.w * bv.z; acc[3][3] += av.w * bv.w;
            }
            __syncthreads();
        }
    }

    // epilogue: bias (+ relu), coalesced float4 store per row
#pragma unroll
    for (int i = 0; i < 4; ++i) {
        int row = m0 + ty * 4 + i;
        if (row < M) {
            int n = n0 + tx * 4;
            float4 v;
            v.x = acc[i][0] + bias[n + 0];
            v.y = acc[i][1] + bias[n + 1];
            v.z = acc[i][2] + bias[n + 2];
            v.w = acc[i][3] + bias[n + 3];
            if (RELU) {
                v.x = fmaxf(v.x, 0.f);
                v.y = fmaxf(v.y, 0.f);
                v.z = fmaxf(v.z, 0.f);
                v.w = fmaxf(v.w, 0.f);
            }
            *(float4*)(out + (size_t)row * NOUT + n) = v;
        }
    }
}

// ---------------------------------------------------------------------------
// launch
// ---------------------------------------------------------------------------

extern "C" void kernel_launch(void* const* d_in, const int* in_sizes, int n_in,
                              void* d_out, int out_size, void* d_ws, size_t ws_size,
                              hipStream_t stream) {
    const float* x = (const float*)d_in[0];
    const int* ei = (const int*)d_in[1];  // [2, E]: row 0 = src, row 1 = dst
    const float* W1l = (const float*)d_in[2];
    const float* b1 = (const float*)d_in[3];
    const float* W1r = (const float*)d_in[4];
    const float* W2l = (const float*)d_in[5];
    const float* b2 = (const float*)d_in[6];
    const float* W2r = (const float*)d_in[7];
    float* out = (float*)d_out;

    const int* src = ei;
    const int* dst = ei + N_EDGES_C;

    // workspace layout (all fully rewritten each call; only counts needs zero)
    int* iw = (int*)d_ws;
    int* counts = iw;                 // 100000 ints
    int* row_start = iw + 100352;     // 100001 ints
    int* cursor = iw + 200704;        // 100000 ints
    int* edge_src = iw + 301056;      // 1600000 ints (ends at 1901056 ints)
    float* fw = (float*)d_ws;
    float* h = fw + 2097152;          // byte offset 8 MiB; 100000*256 floats
    float* meanbuf = fw + 27697152;   // mean1 (100000*128) then mean2 (100000*256)
    // total footprint ~213.2 MB

    hipMemsetAsync(counts, 0, (size_t)N_NODES_C * sizeof(int), stream);

    const int eblocks = (N_EDGES_C + 255) / 256;
    count_kernel<<<eblocks, 256, 0, stream>>>(dst, counts);
    scan_kernel<<<1, 1024, 0, stream>>>(counts, row_start, cursor);
    fill_kernel<<<eblocks, 256, 0, stream>>>(src, dst, cursor, edge_src);

    const int nblocks = (N_NODES_C + 3) / 4;
    // layer 1: mean1 = mean_{src->node} x
    agg_mean128<<<nblocks, 256, 0, stream>>>(x, row_start, edge_src, meanbuf);
    // h = relu(mean1 @ W1_l + x @ W1_r + b1)
    {
        dim3 grid((N_NODES_C + 63) / 64, HID_CH_C / 64);
        gemm_dual<IN_CH_C, HID_CH_C, true>
            <<<grid, 256, 0, stream>>>(meanbuf, W1l, x, W1r, b1, h, N_NODES_C);
    }
    // layer 2: mean2 = mean_{src->node} h
    agg_mean256<<<nblocks, 256, 0, stream>>>(h, row_start, edge_src, meanbuf);
    // out = mean2 @ W2_l + h @ W2_r + b2
    {
        dim3 grid((N_NODES_C + 63) / 64, OUT_CH_C / 64);
        gemm_dual<HID_CH_C, OUT_CH_C, false>
            <<<grid, 256, 0, stream>>>(meanbuf, W2l, h, W2r, b2, out, N_NODES_C);
    }
}

// Round 2
// 742.527 us; speedup vs baseline: 1.8060x; 1.8060x over previous
//
#include <hip/hip_runtime.h>
#include <cstddef>

#define N_NODES_C 100000
#define N_EDGES_C 1600000
#define IN_CH_C 128
#define HID_CH_C 256
#define OUT_CH_C 128
#define SCAN_BLOCKS 391  // ceil(100000/256)

typedef unsigned short u16;
typedef __attribute__((ext_vector_type(8))) short bf16x8;
typedef __attribute__((ext_vector_type(4))) float f32x4;

__device__ __forceinline__ u16 f2bf(float f) {
    unsigned u = __float_as_uint(f);
    u += 0x7fffu + ((u >> 16) & 1);  // round-to-nearest-even
    return (u16)(u >> 16);
}

// ---------------------------------------------------------------------------
// CSR build: count -> block sums -> scan partials -> block scan/write -> fill
// ---------------------------------------------------------------------------

__global__ __launch_bounds__(256) void count_kernel(const int* __restrict__ dst,
                                                    int* __restrict__ counts) {
    int e = blockIdx.x * 256 + threadIdx.x;
    if (e < N_EDGES_C) atomicAdd(&counts[dst[e]], 1);
}

__global__ __launch_bounds__(256) void block_sum(const int* __restrict__ counts,
                                                 int* __restrict__ partials) {
    int t = threadIdx.x;
    int node = blockIdx.x * 256 + t;
    int v = (node < N_NODES_C) ? counts[node] : 0;
#pragma unroll
    for (int off = 32; off > 0; off >>= 1) v += __shfl_down(v, off, 64);
    __shared__ int ws[4];
    if ((t & 63) == 0) ws[t >> 6] = v;
    __syncthreads();
    if (t == 0) partials[blockIdx.x] = ws[0] + ws[1] + ws[2] + ws[3];
}

__global__ __launch_bounds__(512) void scan_partials(const int* __restrict__ partials,
                                                     int* __restrict__ poffset,
                                                     int* __restrict__ row_start) {
    __shared__ int s[512];
    int t = threadIdx.x;
    int v = (t < SCAN_BLOCKS) ? partials[t] : 0;
    s[t] = v;
    __syncthreads();
    for (int off = 1; off < 512; off <<= 1) {
        int u = (t >= off) ? s[t - off] : 0;
        __syncthreads();
        s[t] += u;
        __syncthreads();
    }
    if (t < SCAN_BLOCKS) poffset[t] = s[t] - v;  // exclusive
    if (t == SCAN_BLOCKS - 1) row_start[N_NODES_C] = s[t];
}

__global__ __launch_bounds__(256) void scan_write(const int* __restrict__ counts,
                                                  const int* __restrict__ poffset,
                                                  int* __restrict__ row_start,
                                                  int* __restrict__ cursor) {
    __shared__ int s[256];
    int t = threadIdx.x;
    int node = blockIdx.x * 256 + t;
    int v = (node < N_NODES_C) ? counts[node] : 0;
    s[t] = v;
    __syncthreads();
    for (int off = 1; off < 256; off <<= 1) {
        int u = (t >= off) ? s[t - off] : 0;
        __syncthreads();
        s[t] += u;
        __syncthreads();
    }
    if (node < N_NODES_C) {
        int excl = s[t] - v + poffset[blockIdx.x];
        row_start[node] = excl;
        cursor[node] = excl;
    }
}

__global__ __launch_bounds__(256) void fill_kernel(const int* __restrict__ src,
                                                   const int* __restrict__ dst,
                                                   int* __restrict__ cursor,
                                                   int* __restrict__ edge_src) {
    int e = blockIdx.x * 256 + threadIdx.x;
    if (e < N_EDGES_C) {
        int d = dst[e];
        int pos = atomicAdd(&cursor[d], 1);
        edge_src[pos] = src[e];
    }
}

// ---------------------------------------------------------------------------
// fp32 -> bf16 converters
// ---------------------------------------------------------------------------

__global__ __launch_bounds__(256) void convert_f32_bf16(const float* __restrict__ in,
                                                        u16* __restrict__ out, int n4) {
    int i = blockIdx.x * 256 + threadIdx.x;
    if (i < n4) {
        float4 v = ((const float4*)in)[i];
        ushort4 o;
        o.x = f2bf(v.x); o.y = f2bf(v.y); o.z = f2bf(v.z); o.w = f2bf(v.w);
        ((ushort4*)out)[i] = o;
    }
}

// Transpose+convert all 4 weight matrices: W[K][N] fp32 -> WT[N][K] bf16.
__global__ __launch_bounds__(256) void convert_weights(
    const float* __restrict__ W1l, const float* __restrict__ W1r,
    const float* __restrict__ W2l, const float* __restrict__ W2r,
    u16* __restrict__ T1l, u16* __restrict__ T1r,
    u16* __restrict__ T2l, u16* __restrict__ T2r) {
    int id = blockIdx.x * 256 + threadIdx.x;  // 0 .. 131071
    int which = id >> 15;
    int r = id & 32767;
    if (which == 0) {        // [128][256] -> [256][128]
        int n = r >> 7, k = r & 127;
        T1l[r] = f2bf(W1l[k * 256 + n]);
    } else if (which == 1) {
        int n = r >> 7, k = r & 127;
        T1r[r] = f2bf(W1r[k * 256 + n]);
    } else if (which == 2) {  // [256][128] -> [128][256]
        int n = r >> 8, k = r & 255;
        T2l[r] = f2bf(W2l[k * 128 + n]);
    } else {
        int n = r >> 8, k = r & 255;
        T2r[r] = f2bf(W2r[k * 128 + n]);
    }
}

// ---------------------------------------------------------------------------
// Mean aggregation over bf16 features, fp32 accumulate, bf16 out.
// One wave per destination node. C=128: 4B/lane; C=256: 8B/lane.
// ---------------------------------------------------------------------------

__global__ __launch_bounds__(256) void agg_mean128_bf(const u16* __restrict__ xb,
                                                      const int* __restrict__ row_start,
                                                      const int* __restrict__ edge_src,
                                                      u16* __restrict__ mean) {
    int node = blockIdx.x * 4 + (threadIdx.x >> 6);
    int lane = threadIdx.x & 63;
    if (node >= N_NODES_C) return;
    int beg = row_start[node], end = row_start[node + 1];
    float ax = 0.f, ay = 0.f;
    for (int j = beg; j < end; ++j) {
        int s = edge_src[j];
        unsigned v = *(const unsigned*)(xb + (size_t)s * 128 + lane * 2);
        ax += __uint_as_float((v & 0xffffu) << 16);
        ay += __uint_as_float(v & 0xffff0000u);
    }
    int deg = end - beg;
    float inv = deg > 0 ? 1.f / (float)deg : 0.f;
    unsigned o = (unsigned)f2bf(ax * inv) | ((unsigned)f2bf(ay * inv) << 16);
    *(unsigned*)(mean + (size_t)node * 128 + lane * 2) = o;
}

__global__ __launch_bounds__(256) void agg_mean256_bf(const u16* __restrict__ hb,
                                                      const int* __restrict__ row_start,
                                                      const int* __restrict__ edge_src,
                                                      u16* __restrict__ mean) {
    int node = blockIdx.x * 4 + (threadIdx.x >> 6);
    int lane = threadIdx.x & 63;
    if (node >= N_NODES_C) return;
    int beg = row_start[node], end = row_start[node + 1];
    float a0 = 0.f, a1 = 0.f, a2 = 0.f, a3 = 0.f;
    for (int j = beg; j < end; ++j) {
        int s = edge_src[j];
        uint2 v = *(const uint2*)(hb + (size_t)s * 256 + lane * 4);
        a0 += __uint_as_float((v.x & 0xffffu) << 16);
        a1 += __uint_as_float(v.x & 0xffff0000u);
        a2 += __uint_as_float((v.y & 0xffffu) << 16);
        a3 += __uint_as_float(v.y & 0xffff0000u);
    }
    int deg = end - beg;
    float inv = deg > 0 ? 1.f / (float)deg : 0.f;
    uint2 o;
    o.x = (unsigned)f2bf(a0 * inv) | ((unsigned)f2bf(a1 * inv) << 16);
    o.y = (unsigned)f2bf(a2 * inv) | ((unsigned)f2bf(a3 * inv) << 16);
    *(uint2*)(mean + (size_t)node * 256 + lane * 4) = o;
}

// ---------------------------------------------------------------------------
// Dual-A bf16 MFMA GEMM: OUT[M x NOUT] = act(A1@W1 + A2@W2 + bias)
// A: [M][K] bf16 row-major. WT: [NOUT][K] bf16 (pre-transposed).
// 128x128 block tile, 256 threads (4 waves, 2x2), BK=32, 16x16x32 MFMA.
// Fragment layouts (HW-verified, learn_hip m89/m91):
//   A: lane holds A[m=lane&15][k=(lane>>4)*8 + 0..7]
//   B: lane holds B[k=(lane>>4)*8 + 0..7][n=lane&15]  (read from WT[n][k])
//   C/D: col=lane&15, row=(lane>>4)*4 + reg
// ---------------------------------------------------------------------------

template <int K, int NOUT, bool RELU, bool OUT_BF16>
__global__ __launch_bounds__(256) void gemm_dual_mfma(const u16* __restrict__ A1,
                                                      const u16* __restrict__ W1T,
                                                      const u16* __restrict__ A2,
                                                      const u16* __restrict__ W2T,
                                                      const float* __restrict__ bias,
                                                      void* __restrict__ outv, int M) {
    alignas(16) __shared__ u16 As[128 * 32];
    alignas(16) __shared__ u16 Bs[128 * 32];

    const int tid = threadIdx.x;
    const int lane = tid & 63;
    const int wave = tid >> 6;
    const int qm = lane & 15;
    const int quad = lane >> 4;
    const int r0 = (wave >> 1) * 64;
    const int c0 = (wave & 1) * 64;
    const int m0 = blockIdx.x * 128;
    const int n0 = blockIdx.y * 128;

    f32x4 acc[4][4];
#pragma unroll
    for (int i = 0; i < 4; ++i)
#pragma unroll
        for (int j = 0; j < 4; ++j) acc[i][j] = (f32x4){0.f, 0.f, 0.f, 0.f};

#pragma unroll
    for (int mat = 0; mat < 2; ++mat) {
        const u16* __restrict__ A = mat ? A2 : A1;
        const u16* __restrict__ W = mat ? W2T : W1T;
#pragma unroll
        for (int k0 = 0; k0 < K; k0 += 32) {
            // stage A[128][32] and WT[128][32] tiles: 512 x 16B chunks each
#pragma unroll
            for (int it = 0; it < 2; ++it) {
                int c = it * 256 + tid;
                int row = c >> 2;
                int kc = c & 3;
                uint4 va = make_uint4(0, 0, 0, 0);
                if (m0 + row < M)
                    va = *(const uint4*)(A + (size_t)(m0 + row) * K + k0 + kc * 8);
                *(uint4*)(As + c * 8) = va;
                uint4 vb = *(const uint4*)(W + (size_t)(n0 + row) * K + k0 + kc * 8);
                *(uint4*)(Bs + c * 8) = vb;
            }
            __syncthreads();
            bf16x8 af[4], bf[4];
#pragma unroll
            for (int i = 0; i < 4; ++i)
                af[i] = *(const bf16x8*)(As + (r0 + i * 16 + qm) * 32 + quad * 8);
#pragma unroll
            for (int j = 0; j < 4; ++j)
                bf[j] = *(const bf16x8*)(Bs + (c0 + j * 16 + qm) * 32 + quad * 8);
#pragma unroll
            for (int i = 0; i < 4; ++i)
#pragma unroll
                for (int j = 0; j < 4; ++j)
                    acc[i][j] = __builtin_amdgcn_mfma_f32_16x16x32_bf16(
                        af[i], bf[j], acc[i][j], 0, 0, 0);
            __syncthreads();
        }
    }

    // epilogue
#pragma unroll
    for (int j = 0; j < 4; ++j) {
        int n = n0 + c0 + j * 16 + qm;
        float bv = bias[n];
#pragma unroll
        for (int i = 0; i < 4; ++i) {
            int rbase = m0 + r0 + i * 16 + quad * 4;
#pragma unroll
            for (int r = 0; r < 4; ++r) {
                int row = rbase + r;
                if (row < M) {
                    float val = acc[i][j][r] + bv;
                    if (RELU) val = fmaxf(val, 0.f);
                    if (OUT_BF16)
                        ((u16*)outv)[(size_t)row * NOUT + n] = f2bf(val);
                    else
                        ((float*)outv)[(size_t)row * NOUT + n] = val;
                }
            }
        }
    }
}

// ---------------------------------------------------------------------------
// launch
// ---------------------------------------------------------------------------

extern "C" void kernel_launch(void* const* d_in, const int* in_sizes, int n_in,
                              void* d_out, int out_size, void* d_ws, size_t ws_size,
                              hipStream_t stream) {
    const float* x = (const float*)d_in[0];
    const int* ei = (const int*)d_in[1];
    const float* W1l = (const float*)d_in[2];
    const float* b1 = (const float*)d_in[3];
    const float* W1r = (const float*)d_in[4];
    const float* W2l = (const float*)d_in[5];
    const float* b2 = (const float*)d_in[6];
    const float* W2r = (const float*)d_in[7];
    float* out = (float*)d_out;

    const int* src = ei;
    const int* dst = ei + N_EDGES_C;

    // int workspace region
    int* iw = (int*)d_ws;
    int* counts = iw;                 // 100352
    int* partials = iw + 100352;      // 512
    int* poffset = iw + 100864;       // 512
    int* row_start = iw + 101376;     // 100001 (to 201377)
    int* cursor = iw + 201472;        // 100096
    int* edge_src = iw + 301568;      // 1600000 (to 1901568 ints < 8 MiB)
    // bf16 region at byte offset 8 MiB
    u16* ub = (u16*)((char*)d_ws + (8u << 20));
    u16* x_bf = ub;                   // 12.8M
    u16* h_bf = ub + 12800000;        // 25.6M
    u16* mean1 = ub + 38400000;       // 12.8M
    u16* mean2 = ub + 51200000;       // 25.6M  (total ~162 MB)
    // bf16 weights at tail of int region (after edge_src)
    u16* T1l = (u16*)(iw + 1901568);          // 32768 u16
    u16* T1r = T1l + 32768;
    u16* T2l = T1r + 32768;
    u16* T2r = T2l + 32768;           // ends well before 8 MiB

    hipMemsetAsync(counts, 0, (size_t)N_NODES_C * sizeof(int), stream);

    const int eblocks = (N_EDGES_C + 255) / 256;
    count_kernel<<<eblocks, 256, 0, stream>>>(dst, counts);
    block_sum<<<SCAN_BLOCKS, 256, 0, stream>>>(counts, partials);
    scan_partials<<<1, 512, 0, stream>>>(partials, poffset, row_start);
    scan_write<<<SCAN_BLOCKS, 256, 0, stream>>>(counts, poffset, row_start, cursor);
    fill_kernel<<<eblocks, 256, 0, stream>>>(src, dst, cursor, edge_src);

    convert_f32_bf16<<<(3200000 + 255) / 256, 256, 0, stream>>>(x, x_bf, 3200000);
    convert_weights<<<512, 256, 0, stream>>>(W1l, W1r, W2l, W2r, T1l, T1r, T2l, T2r);

    const int nblocks = (N_NODES_C + 3) / 4;
    agg_mean128_bf<<<nblocks, 256, 0, stream>>>(x_bf, row_start, edge_src, mean1);
    {
        dim3 grid((N_NODES_C + 127) / 128, HID_CH_C / 128);
        gemm_dual_mfma<IN_CH_C, HID_CH_C, true, true>
            <<<grid, 256, 0, stream>>>(mean1, T1l, x_bf, T1r, b1, h_bf, N_NODES_C);
    }
    agg_mean256_bf<<<nblocks, 256, 0, stream>>>(h_bf, row_start, edge_src, mean2);
    {
        dim3 grid((N_NODES_C + 127) / 128, OUT_CH_C / 128);
        gemm_dual_mfma<HID_CH_C, OUT_CH_C, false, false>
            <<<grid, 256, 0, stream>>>(mean2, T2l, h_bf, T2r, b2, out, N_NODES_C);
    }
}

// Round 3
// 564.279 us; speedup vs baseline: 2.3765x; 1.3159x over previous
//
#include <hip/hip_runtime.h>
#include <cstddef>

#define N_NODES_C 100000
#define N_EDGES_C 1600000
#define IN_CH_C 128
#define HID_CH_C 256
#define OUT_CH_C 128
#define SCAN_BLOCKS 391  // ceil(100000/256)

typedef unsigned short u16;
typedef __attribute__((ext_vector_type(8))) short bf16x8;
typedef __attribute__((ext_vector_type(4))) float f32x4;

__device__ __forceinline__ u16 f2bf(float f) {
    unsigned u = __float_as_uint(f);
    u += 0x7fffu + ((u >> 16) & 1);  // round-to-nearest-even
    return (u16)(u >> 16);
}
__device__ __forceinline__ float bf2f(u16 b) {
    return __uint_as_float(((unsigned)b) << 16);
}

// ---------------------------------------------------------------------------
// CSR build: count -> block sums -> scan partials -> block scan/write -> fill
// ---------------------------------------------------------------------------

__global__ __launch_bounds__(256) void count_kernel(const int* __restrict__ dst,
                                                    int* __restrict__ counts) {
    int i = blockIdx.x * 256 + threadIdx.x;  // 4 edges per thread
    if (i * 4 < N_EDGES_C) {
        int4 d = ((const int4*)dst)[i];
        atomicAdd(&counts[d.x], 1);
        atomicAdd(&counts[d.y], 1);
        atomicAdd(&counts[d.z], 1);
        atomicAdd(&counts[d.w], 1);
    }
}

__global__ __launch_bounds__(256) void block_sum(const int* __restrict__ counts,
                                                 int* __restrict__ partials) {
    int t = threadIdx.x;
    int node = blockIdx.x * 256 + t;
    int v = (node < N_NODES_C) ? counts[node] : 0;
#pragma unroll
    for (int off = 32; off > 0; off >>= 1) v += __shfl_down(v, off, 64);
    __shared__ int ws[4];
    if ((t & 63) == 0) ws[t >> 6] = v;
    __syncthreads();
    if (t == 0) partials[blockIdx.x] = ws[0] + ws[1] + ws[2] + ws[3];
}

__global__ __launch_bounds__(512) void scan_partials(const int* __restrict__ partials,
                                                     int* __restrict__ poffset,
                                                     int* __restrict__ row_start) {
    __shared__ int s[512];
    int t = threadIdx.x;
    int v = (t < SCAN_BLOCKS) ? partials[t] : 0;
    s[t] = v;
    __syncthreads();
    for (int off = 1; off < 512; off <<= 1) {
        int u = (t >= off) ? s[t - off] : 0;
        __syncthreads();
        s[t] += u;
        __syncthreads();
    }
    if (t < SCAN_BLOCKS) poffset[t] = s[t] - v;  // exclusive
    if (t == SCAN_BLOCKS - 1) row_start[N_NODES_C] = s[t];
}

__global__ __launch_bounds__(256) void scan_write(const int* __restrict__ counts,
                                                  const int* __restrict__ poffset,
                                                  int* __restrict__ row_start,
                                                  int* __restrict__ cursor) {
    __shared__ int s[256];
    int t = threadIdx.x;
    int node = blockIdx.x * 256 + t;
    int v = (node < N_NODES_C) ? counts[node] : 0;
    s[t] = v;
    __syncthreads();
    for (int off = 1; off < 256; off <<= 1) {
        int u = (t >= off) ? s[t - off] : 0;
        __syncthreads();
        s[t] += u;
        __syncthreads();
    }
    if (node < N_NODES_C) {
        int excl = s[t] - v + poffset[blockIdx.x];
        row_start[node] = excl;
        cursor[node] = excl;
    }
}

__global__ __launch_bounds__(256) void fill_kernel(const int* __restrict__ src,
                                                   const int* __restrict__ dst,
                                                   int* __restrict__ cursor,
                                                   int* __restrict__ edge_src) {
    int i = blockIdx.x * 256 + threadIdx.x;  // 4 edges per thread
    if (i * 4 < N_EDGES_C) {
        int4 s = ((const int4*)src)[i];
        int4 d = ((const int4*)dst)[i];
        edge_src[atomicAdd(&cursor[d.x], 1)] = s.x;
        edge_src[atomicAdd(&cursor[d.y], 1)] = s.y;
        edge_src[atomicAdd(&cursor[d.z], 1)] = s.z;
        edge_src[atomicAdd(&cursor[d.w], 1)] = s.w;
    }
}

// ---------------------------------------------------------------------------
// fp32 -> bf16 converters
// ---------------------------------------------------------------------------

__global__ __launch_bounds__(256) void convert_f32_bf16(const float* __restrict__ in,
                                                        u16* __restrict__ out, int n4) {
    int i = blockIdx.x * 256 + threadIdx.x;
    if (i < n4) {
        float4 v = ((const float4*)in)[i];
        ushort4 o;
        o.x = f2bf(v.x); o.y = f2bf(v.y); o.z = f2bf(v.z); o.w = f2bf(v.w);
        ((ushort4*)out)[i] = o;
    }
}

// Transpose+convert all 4 weight matrices: W[K][N] fp32 -> WT[N][K] bf16.
__global__ __launch_bounds__(256) void convert_weights(
    const float* __restrict__ W1l, const float* __restrict__ W1r,
    const float* __restrict__ W2l, const float* __restrict__ W2r,
    u16* __restrict__ T1l, u16* __restrict__ T1r,
    u16* __restrict__ T2l, u16* __restrict__ T2r) {
    int id = blockIdx.x * 256 + threadIdx.x;  // 0 .. 131071
    int which = id >> 15;
    int r = id & 32767;
    if (which == 0) {        // [128][256] -> [256][128]
        int n = r >> 7, k = r & 127;
        T1l[r] = f2bf(W1l[k * 256 + n]);
    } else if (which == 1) {
        int n = r >> 7, k = r & 127;
        T1r[r] = f2bf(W1r[k * 256 + n]);
    } else if (which == 2) {  // [256][128] -> [128][256]
        int n = r >> 8, k = r & 255;
        T2l[r] = f2bf(W2l[k * 128 + n]);
    } else {
        int n = r >> 8, k = r & 255;
        T2r[r] = f2bf(W2r[k * 128 + n]);
    }
}

// ---------------------------------------------------------------------------
// Mean aggregation over a 128-ch bf16 table, fp32 accumulate, bf16 out.
// One wave per destination node, 2 channels/lane. Edge indices are batch-
// loaded by lanes and broadcast via __shfl; gather unrolled x4 for MLP.
// ---------------------------------------------------------------------------

__global__ __launch_bounds__(256) void agg_mean128(const u16* __restrict__ tbl,
                                                   const int* __restrict__ row_start,
                                                   const int* __restrict__ edge_src,
                                                   u16* __restrict__ mean) {
    int node = blockIdx.x * 4 + (threadIdx.x >> 6);
    int lane = threadIdx.x & 63;
    if (node >= N_NODES_C) return;
    int beg = row_start[node], end = row_start[node + 1];
    float ax = 0.f, ay = 0.f;
    for (int j0 = beg; j0 < end; j0 += 64) {
        int nn = end - j0;
        if (nn > 64) nn = 64;
        int idx = 0;
        if (j0 + lane < end) idx = edge_src[j0 + lane];
        int t = 0;
        for (; t + 4 <= nn; t += 4) {
            int s0 = __shfl(idx, t, 64);
            int s1 = __shfl(idx, t + 1, 64);
            int s2 = __shfl(idx, t + 2, 64);
            int s3 = __shfl(idx, t + 3, 64);
            unsigned v0 = *(const unsigned*)(tbl + (size_t)s0 * 128 + lane * 2);
            unsigned v1 = *(const unsigned*)(tbl + (size_t)s1 * 128 + lane * 2);
            unsigned v2 = *(const unsigned*)(tbl + (size_t)s2 * 128 + lane * 2);
            unsigned v3 = *(const unsigned*)(tbl + (size_t)s3 * 128 + lane * 2);
            ax += __uint_as_float((v0 & 0xffffu) << 16);
            ay += __uint_as_float(v0 & 0xffff0000u);
            ax += __uint_as_float((v1 & 0xffffu) << 16);
            ay += __uint_as_float(v1 & 0xffff0000u);
            ax += __uint_as_float((v2 & 0xffffu) << 16);
            ay += __uint_as_float(v2 & 0xffff0000u);
            ax += __uint_as_float((v3 & 0xffffu) << 16);
            ay += __uint_as_float(v3 & 0xffff0000u);
        }
        for (; t < nn; ++t) {
            int s = __shfl(idx, t, 64);
            unsigned v = *(const unsigned*)(tbl + (size_t)s * 128 + lane * 2);
            ax += __uint_as_float((v & 0xffffu) << 16);
            ay += __uint_as_float(v & 0xffff0000u);
        }
    }
    int deg = end - beg;
    float inv = deg > 0 ? 1.f / (float)deg : 0.f;
    unsigned o = (unsigned)f2bf(ax * inv) | ((unsigned)f2bf(ay * inv) << 16);
    *(unsigned*)(mean + (size_t)node * 128 + lane * 2) = o;
}

// ---------------------------------------------------------------------------
// bf16 MFMA GEMM: OUT[M x NOUT] = act(A1@W1 [+ A2@W2] [+ resid] [+ bias])
// A: [M][K] bf16 row-major. WT: [NOUT][K] bf16 (pre-transposed).
// 128x128 block tile, 256 threads (4 waves, 2x2), BK=32, 16x16x32 MFMA.
// Staging via global_load_lds width=16 (wave-uniform LDS base + lane*16).
// OOB tail rows (m0+row >= M) load garbage; MFMA dataflow confines it to
// output rows >= M which the epilogue discards.
// Fragment layouts (HW-verified, learn_hip m89/m91):
//   A: lane holds A[m=lane&15][k=(lane>>4)*8 + 0..7]
//   B: lane holds B[k=(lane>>4)*8 + 0..7][n=lane&15]  (read from WT[n][k])
//   C/D: col=lane&15, row=(lane>>4)*4 + reg
// ---------------------------------------------------------------------------

template <int K, int NOUT, bool DUAL, bool RELU, bool HAS_BIAS, bool RES, bool OUT_BF16>
__global__ __launch_bounds__(256) void gemm_mfma(const u16* __restrict__ A1,
                                                 const u16* __restrict__ W1T,
                                                 const u16* __restrict__ A2,
                                                 const u16* __restrict__ W2T,
                                                 const u16* __restrict__ resid,
                                                 const float* __restrict__ bias,
                                                 void* __restrict__ outv, int M) {
    alignas(16) __shared__ u16 As[128 * 32];
    alignas(16) __shared__ u16 Bs[128 * 32];

    const int tid = threadIdx.x;
    const int lane = tid & 63;
    const int wave = tid >> 6;
    const int qm = lane & 15;
    const int quad = lane >> 4;
    const int r0 = (wave >> 1) * 64;
    const int c0 = (wave & 1) * 64;
    const int m0 = blockIdx.x * 128;
    const int n0 = blockIdx.y * 128;

    f32x4 acc[4][4];
#pragma unroll
    for (int i = 0; i < 4; ++i)
#pragma unroll
        for (int j = 0; j < 4; ++j) acc[i][j] = (f32x4){0.f, 0.f, 0.f, 0.f};

    const int NMAT = DUAL ? 2 : 1;
#pragma unroll
    for (int mat = 0; mat < NMAT; ++mat) {
        const u16* __restrict__ A = mat ? A2 : A1;
        const u16* __restrict__ W = mat ? W2T : W1T;
#pragma unroll
        for (int k0 = 0; k0 < K; k0 += 32) {
            // stage A[128][32] and WT[128][32] tiles: 512 x 16B chunks each
#pragma unroll
            for (int it = 0; it < 2; ++it) {
                int c = it * 256 + tid;
                int row = c >> 2;
                int kc = c & 3;
                const u16* ga = A + (size_t)(m0 + row) * K + k0 + kc * 8;
                const u16* gb = W + (size_t)(n0 + row) * K + k0 + kc * 8;
                __builtin_amdgcn_global_load_lds(
                    (const __attribute__((address_space(1))) unsigned*)ga,
                    (__attribute__((address_space(3))) unsigned*)(As + c * 8), 16, 0, 0);
                __builtin_amdgcn_global_load_lds(
                    (const __attribute__((address_space(1))) unsigned*)gb,
                    (__attribute__((address_space(3))) unsigned*)(Bs + c * 8), 16, 0, 0);
            }
            __syncthreads();
            bf16x8 af[4], bfr[4];
#pragma unroll
            for (int i = 0; i < 4; ++i)
                af[i] = *(const bf16x8*)(As + (r0 + i * 16 + qm) * 32 + quad * 8);
#pragma unroll
            for (int j = 0; j < 4; ++j)
                bfr[j] = *(const bf16x8*)(Bs + (c0 + j * 16 + qm) * 32 + quad * 8);
#pragma unroll
            for (int i = 0; i < 4; ++i)
#pragma unroll
                for (int j = 0; j < 4; ++j)
                    acc[i][j] = __builtin_amdgcn_mfma_f32_16x16x32_bf16(
                        af[i], bfr[j], acc[i][j], 0, 0, 0);
            __syncthreads();
        }
    }

    // epilogue
#pragma unroll
    for (int j = 0; j < 4; ++j) {
        int n = n0 + c0 + j * 16 + qm;
        float bv = HAS_BIAS ? bias[n] : 0.f;
#pragma unroll
        for (int i = 0; i < 4; ++i) {
            int rbase = m0 + r0 + i * 16 + quad * 4;
#pragma unroll
            for (int r = 0; r < 4; ++r) {
                int row = rbase + r;
                if (row < M) {
                    float val = acc[i][j][r] + bv;
                    if (RES) val += bf2f(resid[(size_t)row * NOUT + n]);
                    if (RELU) val = fmaxf(val, 0.f);
                    if (OUT_BF16)
                        ((u16*)outv)[(size_t)row * NOUT + n] = f2bf(val);
                    else
                        ((float*)outv)[(size_t)row * NOUT + n] = val;
                }
            }
        }
    }
}

// ---------------------------------------------------------------------------
// launch
// ---------------------------------------------------------------------------

extern "C" void kernel_launch(void* const* d_in, const int* in_sizes, int n_in,
                              void* d_out, int out_size, void* d_ws, size_t ws_size,
                              hipStream_t stream) {
    const float* x = (const float*)d_in[0];
    const int* ei = (const int*)d_in[1];
    const float* W1l = (const float*)d_in[2];
    const float* b1 = (const float*)d_in[3];
    const float* W1r = (const float*)d_in[4];
    const float* W2l = (const float*)d_in[5];
    const float* b2 = (const float*)d_in[6];
    const float* W2r = (const float*)d_in[7];
    float* out = (float*)d_out;

    const int* src = ei;
    const int* dst = ei + N_EDGES_C;

    // int workspace region (first 8 MiB)
    int* iw = (int*)d_ws;
    int* counts = iw;                 // [0, 100352)
    int* partials = iw + 100352;      // 512
    int* poffset = iw + 100864;       // 512
    int* row_start = iw + 101376;     // 100001 -> pad to 201728
    int* cursor = iw + 201728;        // 100352
    int* edge_src = iw + 302080;      // 1600000 -> ends 1902080 ints
    u16* T1l = (u16*)(iw + 1902080);  // 4 x 32768 u16 = 256 KB, ends < 8 MiB
    u16* T1r = T1l + 32768;
    u16* T2l = T1r + 32768;
    u16* T2r = T2l + 32768;
    // bf16 region at byte offset 8 MiB
    u16* ub = (u16*)((char*)d_ws + (8u << 20));
    u16* x_bf = ub;                   // 12.8M u16
    u16* h_bf = ub + 12800000;        // 25.6M
    u16* mean1 = ub + 38400000;       // 12.8M
    u16* p2 = ub + 51200000;          // 12.8M
    u16* mean2p = ub + 64000000;      // 12.8M (total ~161.6 MB)

    hipMemsetAsync(counts, 0, (size_t)N_NODES_C * sizeof(int), stream);

    const int e4blocks = (N_EDGES_C / 4 + 255) / 256;
    count_kernel<<<e4blocks, 256, 0, stream>>>(dst, counts);
    block_sum<<<SCAN_BLOCKS, 256, 0, stream>>>(counts, partials);
    scan_partials<<<1, 512, 0, stream>>>(partials, poffset, row_start);
    scan_write<<<SCAN_BLOCKS, 256, 0, stream>>>(counts, poffset, row_start, cursor);
    fill_kernel<<<e4blocks, 256, 0, stream>>>(src, dst, cursor, edge_src);

    convert_f32_bf16<<<(3200000 + 255) / 256, 256, 0, stream>>>(x, x_bf, 3200000);
    convert_weights<<<512, 256, 0, stream>>>(W1l, W1r, W2l, W2r, T1l, T1r, T2l, T2r);

    const int nblocks = (N_NODES_C + 3) / 4;
    // layer 1: mean1 = mean_{src->node} x   (128-ch gather)
    agg_mean128<<<nblocks, 256, 0, stream>>>(x_bf, row_start, edge_src, mean1);
    // h = relu(mean1 @ W1_l + x @ W1_r + b1)
    {
        dim3 grid((N_NODES_C + 127) / 128, HID_CH_C / 128);
        gemm_mfma<IN_CH_C, HID_CH_C, true, true, true, false, true>
            <<<grid, 256, 0, stream>>>(mean1, T1l, x_bf, T1r, nullptr, b1, h_bf,
                                       N_NODES_C);
    }
    // layer 2 with projection-before-aggregation:
    // p2 = h @ W2_l  (project 256 -> 128 BEFORE the gather)
    {
        dim3 grid((N_NODES_C + 127) / 128, OUT_CH_C / 128);
        gemm_mfma<HID_CH_C, OUT_CH_C, false, false, false, false, true>
            <<<grid, 256, 0, stream>>>(h_bf, T2l, nullptr, nullptr, nullptr, nullptr,
                                       p2, N_NODES_C);
    }
    // mean2p = mean_{src->node} p2   (128-ch gather, halved traffic)
    agg_mean128<<<nblocks, 256, 0, stream>>>(p2, row_start, edge_src, mean2p);
    // out = mean2p + h @ W2_r + b2
    {
        dim3 grid((N_NODES_C + 127) / 128, OUT_CH_C / 128);
        gemm_mfma<HID_CH_C, OUT_CH_C, false, false, true, true, false>
            <<<grid, 256, 0, stream>>>(h_bf, T2r, nullptr, nullptr, mean2p, b2, out,
                                       N_NODES_C);
    }
}